// Round 6
// baseline (272.429 us; speedup 1.0000x reference)
//
#include <hip/hip_runtime.h>
#include <hip/hip_bf16.h>

typedef short bf8 __attribute__((ext_vector_type(8)));   // 8 bf16 (4 VGPRs)
typedef float f4 __attribute__((ext_vector_type(4)));

#define S_LEN 4096
#define H_DIM 1024
#define D_DIM 512
#define B_DIM 16
#define OUT_BASE ((size_t)B_DIM * S_LEN * H_DIM)

// float -> bf16 bits, round-to-nearest-even
static __device__ __forceinline__ unsigned short f2bf(float f) {
    union { float f; unsigned int u; } c; c.f = f;
    unsigned int u = c.u;
    return (unsigned short)((u + 0x7FFFu + ((u >> 16) & 1u)) >> 16);
}

// cW1 [K=1024][N=512] f32 row-major  ->  wT [N=512][K=1024] bf16
__global__ __launch_bounds__(256) void prep_transpose(const float* __restrict__ cW1,
                                                      unsigned short* __restrict__ wT) {
    __shared__ float tile[64][68];
    const int kt = blockIdx.x >> 3;
    const int nt = blockIdx.x & 7;
    const int tr = threadIdx.x >> 4;
    const int tc = threadIdx.x & 15;
#pragma unroll
    for (int i = 0; i < 4; ++i) {
        const f4 v = *(const f4*)(cW1 + (size_t)(kt * 64 + i * 16 + tr) * D_DIM + nt * 64 + tc * 4);
        tile[i * 16 + tr][tc * 4 + 0] = v.x;
        tile[i * 16 + tr][tc * 4 + 1] = v.y;
        tile[i * 16 + tr][tc * 4 + 2] = v.z;
        tile[i * 16 + tr][tc * 4 + 3] = v.w;
    }
    __syncthreads();
#pragma unroll
    for (int i = 0; i < 4; ++i) {
        const int n = i * 16 + tr;
        ushort4 o;
        o.x = f2bf(tile[tc * 4 + 0][n]);
        o.y = f2bf(tile[tc * 4 + 1][n]);
        o.z = f2bf(tile[tc * 4 + 2][n]);
        o.w = f2bf(tile[tc * 4 + 3][n]);
        *(ushort4*)(wT + (size_t)(nt * 64 + n) * H_DIM + kt * 64 + tc * 4) = o;
    }
}

// Fused contiguous stream: each block owns a CONTIGUOUS 256-KB slab (one b, 64 consecutive s).
// Reads it sequentially, writes the states-copy sequentially, stages all K=1024 as bf16 into
// LDS (swizzled) once. K-loop is barrier-free: B fragments load per-MFMA from L2-resident wT.
// Epilogue writes per-(b,s) sigmoid/16 partials to ws (reduced over b by reduce_comp).
__global__ __launch_bounds__(512, 2) void fused_stream_kernel(
    const float* __restrict__ states,
    const unsigned short* __restrict__ wT,
    const float* __restrict__ cb1,
    const float* __restrict__ cW2,
    const float* __restrict__ cb2,
    float* __restrict__ out,
    float* __restrict__ part_ws) {
    __shared__ unsigned short As[64][1024];   // 128 KB, XOR-swizzled 16B slots

    const int t = threadIdx.x;
    const int lane = t & 63;
    const int wv = t >> 6;        // 0..7 : wave n-slice [wv*64, +64)
    const int la = lane & 15;
    const int lg = lane >> 4;
    const int b = blockIdx.x >> 6;
    const int s0 = (blockIdx.x & 63) * 64;
    const size_t base = ((size_t)b * S_LEN + s0) * H_DIM;

    // ---- staging: thread t owns row (t>>3), k-span [seg*32 .. ) per quarter ----
    const int row = t >> 3;       // s-offset 0..63
    const int seg = t & 7;
    const int rx = row & 7;
    const float* gp = states + base + (size_t)row * H_DIM + seg * 32;
    float* op = out + base + (size_t)row * H_DIM + seg * 32;
    char* lrow = (char*)&As[0][0] + row * 2048;

#pragma unroll
    for (int q = 0; q < 4; ++q) {
        f4 v[8];
#pragma unroll
        for (int i = 0; i < 8; ++i) v[i] = *(const f4*)(gp + q * 256 + i * 4);
#pragma unroll
        for (int i = 0; i < 8; ++i) *(f4*)(op + q * 256 + i * 4) = v[i];   // fused copy-out
#pragma unroll
        for (int p = 0; p < 4; ++p) {
            bf8 pk;
            pk[0] = (short)f2bf(v[2 * p].x);     pk[1] = (short)f2bf(v[2 * p].y);
            pk[2] = (short)f2bf(v[2 * p].z);     pk[3] = (short)f2bf(v[2 * p].w);
            pk[4] = (short)f2bf(v[2 * p + 1].x); pk[5] = (short)f2bf(v[2 * p + 1].y);
            pk[6] = (short)f2bf(v[2 * p + 1].z); pk[7] = (short)f2bf(v[2 * p + 1].w);
            const int sl = (q * 32 + seg * 4 + p) ^ rx;   // 16-B slot, swizzled
            *(bf8*)(lrow + sl * 16) = pk;
        }
    }
    __syncthreads();

    // ---- barrier-free K-loop: A from LDS, B straight from L2 ----
    f4 acc[4][4];
#pragma unroll
    for (int a = 0; a < 4; ++a)
#pragma unroll
        for (int c = 0; c < 4; ++c) acc[a][c] = f4{0.f, 0.f, 0.f, 0.f};

    const unsigned short* bp = wT + (size_t)(wv * 64 + la) * H_DIM + lg * 8;
    bf8 bcur[4];
#pragma unroll
    for (int fc = 0; fc < 4; ++fc)
        bcur[fc] = *(const bf8*)(bp + (size_t)fc * 16 * H_DIM);

#pragma unroll
    for (int ch = 0; ch < 32; ++ch) {
        bf8 bnext[4];
        if (ch < 31) {
#pragma unroll
            for (int fc = 0; fc < 4; ++fc)
                bnext[fc] = *(const bf8*)(bp + (size_t)fc * 16 * H_DIM + (ch + 1) * 32);
        }
        bf8 af[4];
#pragma unroll
        for (int fr = 0; fr < 4; ++fr) {
            const int sl = (ch * 4 + lg) ^ (la & 7);
            af[fr] = *(const bf8*)((char*)&As[0][0] + (fr * 16 + la) * 2048 + sl * 16);
        }
#pragma unroll
        for (int fr = 0; fr < 4; ++fr)
#pragma unroll
            for (int fc = 0; fc < 4; ++fc)
                acc[fr][fc] = __builtin_amdgcn_mfma_f32_16x16x32_bf16(af[fr], bcur[fc], acc[fr][fc], 0, 0, 0);
        if (ch < 31) {
#pragma unroll
            for (int fc = 0; fc < 4; ++fc) bcur[fc] = bnext[fc];
        }
    }

    // ---- epilogue: relu + dot(cW2) + sigmoid/16 -> partial per (b, s) ----
    float w2v[4], b1v[4];
#pragma unroll
    for (int fc = 0; fc < 4; ++fc) {
        const int d = wv * 64 + fc * 16 + la;
        w2v[fc] = cW2[d];
        b1v[fc] = cb1[d];
    }
    __syncthreads();                       // done reading As -> overlay scratch
    float* part = (float*)&As[0][0];       // [64][8]
#pragma unroll
    for (int fr = 0; fr < 4; ++fr) {
#pragma unroll
        for (int rg = 0; rg < 4; ++rg) {
            float p = 0.f;
#pragma unroll
            for (int fc = 0; fc < 4; ++fc)
                p += fmaxf(acc[fr][fc][rg] + b1v[fc], 0.f) * w2v[fc];
#pragma unroll
            for (int off = 1; off < 16; off <<= 1)
                p += __shfl_xor(p, off, 64);   // sum over 16 lane-columns (n)
            if (la == 0) part[(fr * 16 + lg * 4 + rg) * 8 + wv] = p;
        }
    }
    __syncthreads();
    if (t < 64) {
        float sum = cb2[0];
#pragma unroll
        for (int ww = 0; ww < 8; ++ww) sum += part[t * 8 + ww];
        const float sg = 1.f / (1.f + __expf(-sum));
        part_ws[(size_t)b * S_LEN + s0 + t] = sg * (1.f / 16.f);
    }
}

// comp_mean[s] = sum_b partial[b][s]; also steps_used ≡ 1 (rb<=128-t can never make
// trunc(rb/(S-t+1))>=2; negative rb clips to 1) and rb_final = 128-4096 = -3968.
__global__ __launch_bounds__(256) void reduce_comp(const float* __restrict__ part_ws,
                                                   float* __restrict__ out) {
    const int s = blockIdx.x * 256 + threadIdx.x;
    float sum = 0.f;
#pragma unroll
    for (int b = 0; b < B_DIM; ++b) sum += part_ws[(size_t)b * S_LEN + s];
    out[OUT_BASE + S_LEN + s] = sum;     // comp_mean
    out[OUT_BASE + s] = 1.0f;            // steps_used
    if (s == 0) out[OUT_BASE + 2 * S_LEN] = -3968.0f;  // rb_final.mean()
}

extern "C" void kernel_launch(void* const* d_in, const int* in_sizes, int n_in,
                              void* d_out, int out_size, void* d_ws, size_t ws_size,
                              hipStream_t stream) {
    const float* states = (const float*)d_in[0];
    const float* cW1 = (const float*)d_in[5];
    const float* cb1 = (const float*)d_in[6];
    const float* cW2 = (const float*)d_in[7];
    const float* cb2 = (const float*)d_in[8];
    float* out = (float*)d_out;
    unsigned short* wT = (unsigned short*)d_ws;                 // 1 MB bf16 [512][1024]
    float* part_ws = (float*)((char*)d_ws + (size_t)D_DIM * H_DIM * 2);  // 256 KB [16][4096]

    hipLaunchKernelGGL(prep_transpose, dim3(128), dim3(256), 0, stream, cW1, wT);
    hipLaunchKernelGGL(fused_stream_kernel, dim3(1024), dim3(512), 0, stream,
                       states, wT, cb1, cW2, cb2, out, part_ws);
    hipLaunchKernelGGL(reduce_comp, dim3(16), dim3(256), 0, stream, part_ws, out);
}